// Round 1
// baseline (372.531 us; speedup 1.0000x reference)
//
#include <hip/hip_runtime.h>

namespace {
constexpr int B = 2, C = 72, O = 72, H = 180, W = 320;
constexpr int K = 9, G = 9, Cg = 8, Og = 8;
constexpr int OFFC = 2 * K;           // 18 offset channels
constexpr int HW = H * W;             // 57600
constexpr size_t OFF_ELEMS = (size_t)B * OFFC * HW;   // 2,073,600 floats
constexpr int W1_ELEMS = OFFC * C * 9;                // 11664
constexpr int W2_ELEMS = O * Cg * 9;                  // 5184
}

// ---------------------------------------------------------------------------
// Setup: transpose weights for contiguous wave-uniform (scalar) access.
//   w1t[ic][tap][oc]   <- off_w[oc][ic][tap]      (18,72,3,3)
//   w2t[g][k][cg][og]  <- weight[g*8+og][cg][k]   (72,8,3,3)
// ---------------------------------------------------------------------------
__global__ __launch_bounds__(256) void transpose_weights(
    const float* __restrict__ off_w,
    const float* __restrict__ weight,
    float* __restrict__ w1t,
    float* __restrict__ w2t)
{
    int i = blockIdx.x * blockDim.x + threadIdx.x;
    if (i < W1_ELEMS) {
        int oc = i % OFFC;
        int tap = (i / OFFC) % 9;
        int ic = i / (OFFC * 9);
        w1t[i] = off_w[(oc * C + ic) * 9 + tap];
    }
    if (i < W2_ELEMS) {
        int og = i % Og;
        int cg = (i / Og) % Cg;
        int k = (i / (Og * Cg)) % K;
        int g = i / (Og * Cg * K);
        w2t[i] = weight[((g * Og + og) * Cg + cg) * 9 + k];
    }
}

// ---------------------------------------------------------------------------
// Kernel 1: 3x3 conv (C=72 -> 18) + bias.  One thread per output pixel,
// computing all 18 channels (each input load feeds 18 FMAs).
// ---------------------------------------------------------------------------
__global__ __launch_bounds__(256) void offset_conv(
    const float* __restrict__ x,      // (B, C, H, W) = offset_feat
    const float* __restrict__ w1t,    // [ic][tap][oc]
    const float* __restrict__ bias,   // (18,)
    float* __restrict__ offs)         // (B, 18, H, W)
{
    int idx = blockIdx.x * blockDim.x + threadIdx.x;
    int xw = idx % W;
    int yh = (idx / W) % H;
    int b = idx / HW;

    float acc[OFFC];
    #pragma unroll
    for (int oc = 0; oc < OFFC; ++oc) acc[oc] = bias[oc];

    const float* xb = x + (size_t)b * C * HW;
    for (int ic = 0; ic < C; ++ic) {
        const float* xc = xb + ic * HW;
        #pragma unroll
        for (int ky = 0; ky < 3; ++ky) {
            int yy = yh + ky - 1;
            #pragma unroll
            for (int kx = 0; kx < 3; ++kx) {
                int xx = xw + kx - 1;
                bool v = (yy >= 0) & (yy < H) & (xx >= 0) & (xx < W);
                float val = v ? xc[yy * W + xx] : 0.0f;
                const float* wp = w1t + (ic * 9 + ky * 3 + kx) * OFFC;
                #pragma unroll
                for (int oc = 0; oc < OFFC; ++oc)
                    acc[oc] = fmaf(val, wp[oc], acc[oc]);
            }
        }
    }
    float* op = offs + (size_t)b * OFFC * HW + yh * W + xw;
    #pragma unroll
    for (int oc = 0; oc < OFFC; ++oc) op[(size_t)oc * HW] = acc[oc];
}

// ---------------------------------------------------------------------------
// Kernel 2: deformable grouped conv. One thread per (pixel, group):
// 9 taps x 8 input channels bilinear-sampled, accumulated into 8 outputs.
// g is wave-uniform (HW % 256 == 0) -> readfirstlane for scalar weight loads.
// ---------------------------------------------------------------------------
__global__ __launch_bounds__(256) void deform_conv(
    const float* __restrict__ x,      // (B, C, H, W) = input
    const float* __restrict__ offs,   // (B, 18, H, W)
    const float* __restrict__ w2t,    // [g][k][cg][og]
    float* __restrict__ out)          // (B, O, H, W)
{
    int idx = blockIdx.x * blockDim.x + threadIdx.x;
    int xw = idx % W;
    int yh = (idx / W) % H;
    int g = (idx / HW) % G;
    int b = idx / (HW * G);

    int gu = __builtin_amdgcn_readfirstlane(g);
    const float* wg = w2t + gu * (K * Cg * Og);
    const float* xg = x + ((size_t)b * C + gu * Cg) * HW;
    const float* offp = offs + (size_t)b * OFFC * HW + yh * W + xw;

    float acc[Og];
    #pragma unroll
    for (int og = 0; og < Og; ++og) acc[og] = 0.f;

    #pragma unroll
    for (int k = 0; k < K; ++k) {
        float dy = offp[(size_t)(2 * k) * HW];
        float dx = offp[(size_t)(2 * k + 1) * HW];
        float py = (float)(yh + k / 3 - 1) + dy;
        float px = (float)(xw + k % 3 - 1) + dx;
        float fy = floorf(py);
        float fx = floorf(px);
        int y0 = (int)fy, x0 = (int)fx;
        int y1 = y0 + 1, x1 = x0 + 1;
        float wy1 = py - fy, wx1 = px - fx;
        float wy0 = 1.f - wy1, wx0 = 1.f - wx1;
        bool vy0 = (y0 >= 0) & (y0 < H);
        bool vy1 = (y1 >= 0) & (y1 < H);
        bool vx0 = (x0 >= 0) & (x0 < W);
        bool vx1 = (x1 >= 0) & (x1 < W);
        float h00 = (vy0 & vx0) ? wy0 * wx0 : 0.f;
        float h01 = (vy0 & vx1) ? wy0 * wx1 : 0.f;
        float h10 = (vy1 & vx0) ? wy1 * wx0 : 0.f;
        float h11 = (vy1 & vx1) ? wy1 * wx1 : 0.f;
        int y0c = min(max(y0, 0), H - 1);
        int y1c = min(max(y1, 0), H - 1);
        int x0c = min(max(x0, 0), W - 1);
        int x1c = min(max(x1, 0), W - 1);
        int i00 = y0c * W + x0c;
        int i01 = y0c * W + x1c;
        int i10 = y1c * W + x0c;
        int i11 = y1c * W + x1c;
        const float* wk = wg + k * (Cg * Og);
        #pragma unroll
        for (int cg = 0; cg < Cg; ++cg) {
            const float* xc = xg + cg * HW;
            float v = h00 * xc[i00] + h01 * xc[i01]
                    + h10 * xc[i10] + h11 * xc[i11];
            #pragma unroll
            for (int og = 0; og < Og; ++og)
                acc[og] = fmaf(v, wk[cg * Og + og], acc[og]);
        }
    }
    float* op = out + ((size_t)b * O + gu * Og) * HW + yh * W + xw;
    #pragma unroll
    for (int og = 0; og < Og; ++og) op[(size_t)og * HW] = acc[og];
}

extern "C" void kernel_launch(void* const* d_in, const int* in_sizes, int n_in,
                              void* d_out, int out_size, void* d_ws, size_t ws_size,
                              hipStream_t stream) {
    const float* input       = (const float*)d_in[0];
    const float* offset_feat = (const float*)d_in[1];
    const float* weight      = (const float*)d_in[2];
    const float* off_w       = (const float*)d_in[3];
    const float* off_b       = (const float*)d_in[4];
    float* out = (float*)d_out;

    float* offs = (float*)d_ws;
    float* w1t = offs + OFF_ELEMS;
    float* w2t = w1t + W1_ELEMS;

    transpose_weights<<<(W1_ELEMS + 255) / 256, 256, 0, stream>>>(off_w, weight, w1t, w2t);
    offset_conv<<<(B * HW) / 256, 256, 0, stream>>>(offset_feat, w1t, off_b, offs);
    deform_conv<<<(B * G * HW) / 256, 256, 0, stream>>>(input, offs, w2t, out);
}

// Round 2
// 368.562 us; speedup vs baseline: 1.0108x; 1.0108x over previous
//
#include <hip/hip_runtime.h>

namespace {
constexpr int B = 2, C = 72, O = 72, H = 180, W = 320;
constexpr int K = 9, G = 9, Cg = 8, Og = 8;
constexpr int OFFC = 2 * K;           // 18 offset channels
constexpr int HW = H * W;             // 57600
constexpr size_t OFF_ELEMS = (size_t)B * OFFC * HW;   // 2,073,600 floats
constexpr int W1_ELEMS = OFFC * C * 9;                // 11664
constexpr int W2_ELEMS = O * Cg * 9;                  // 5184
constexpr int ICW = C / 4;            // 18 input channels per wave
}

// ---------------------------------------------------------------------------
// Setup: transpose weights for contiguous wave-uniform (scalar) access.
//   w1t[ic][tap][oc]   <- off_w[oc][ic][tap]      (18,72,3,3)
//   w2t[g][k][cg][og]  <- weight[g*8+og][cg][k]   (72,8,3,3)
// ---------------------------------------------------------------------------
__global__ __launch_bounds__(256) void transpose_weights(
    const float* __restrict__ off_w,
    const float* __restrict__ weight,
    float* __restrict__ w1t,
    float* __restrict__ w2t)
{
    int i = blockIdx.x * blockDim.x + threadIdx.x;
    if (i < W1_ELEMS) {
        int oc = i % OFFC;
        int tap = (i / OFFC) % 9;
        int ic = i / (OFFC * 9);
        w1t[i] = off_w[(oc * C + ic) * 9 + tap];
    }
    if (i < W2_ELEMS) {
        int og = i % Og;
        int cg = (i / Og) % Cg;
        int k = (i / (Og * Cg)) % K;
        int g = i / (Og * Cg * K);
        w2t[i] = weight[((g * Og + og) * Cg + cg) * 9 + k];
    }
}

// ---------------------------------------------------------------------------
// Kernel 1: 3x3 conv (C=72 -> 18) + bias.
// Block = 256 threads = 4 waves; block covers 64 consecutive pixels (one row
// segment, since W % 64 == 0); wave w reduces input channels [18w, 18w+18).
// Partials meet in LDS; reduce adds bias and writes coalesced.
// Occupancy: 1800 blocks = 7200 waves (~88%) vs 450 blocks (~22%) before.
// ---------------------------------------------------------------------------
__global__ __launch_bounds__(256) void offset_conv(
    const float* __restrict__ x,      // (B, C, H, W) = offset_feat
    const float* __restrict__ w1t,    // [ic][tap][oc]
    const float* __restrict__ bias,   // (18,)
    float* __restrict__ offs)         // (B, 18, H, W)
{
    __shared__ float red[4 * 64 * OFFC];   // 18432 B, linear -> conflict-free
    const int lane = threadIdx.x & 63;
    const int wave = threadIdx.x >> 6;

    const int g0 = blockIdx.x * 64;        // pixel index over B*HW
    const int b = g0 / HW;
    const int pix = g0 - b * HW;           // multiple of 64; one row segment
    const int yh = pix / W;
    const int x0b = pix - yh * W;
    const int xw = x0b + lane;

    float acc[OFFC];
    #pragma unroll
    for (int oc = 0; oc < OFFC; ++oc) acc[oc] = 0.f;

    const float* xb = x + (size_t)b * C * HW;
    const int ic0 = wave * ICW;

    // row validity is wave-uniform (whole block is one image row)
    const bool rv0 = (yh - 1) >= 0;
    const bool rv2 = (yh + 1) < H;

    #pragma unroll 2
    for (int ici = 0; ici < ICW; ++ici) {
        const int ic = ic0 + ici;
        const float* xc = xb + ic * HW;
        #pragma unroll
        for (int ky = 0; ky < 3; ++ky) {
            const int yy = yh + ky - 1;
            const bool rowv = (ky == 0) ? rv0 : (ky == 2 ? rv2 : true);
            if (!rowv) continue;           // uniform branch
            const float* xr = xc + yy * W;
            #pragma unroll
            for (int kx = 0; kx < 3; ++kx) {
                const int xx = xw + kx - 1;
                const bool v = (xx >= 0) & (xx < W);
                const float val = v ? xr[xx] : 0.0f;
                const float* wp = w1t + (ic * 9 + ky * 3 + kx) * OFFC;
                #pragma unroll
                for (int oc = 0; oc < OFFC; ++oc)
                    acc[oc] = fmaf(val, wp[oc], acc[oc]);
            }
        }
    }

    #pragma unroll
    for (int oc = 0; oc < OFFC; ++oc)
        red[(wave * 64 + lane) * OFFC + oc] = acc[oc];
    __syncthreads();

    // 64*18 = 1152 outputs, 256 threads -> 4.5 elems each; px fast within oc
    for (int e = threadIdx.x; e < 64 * OFFC; e += 256) {
        const int oc = e / 64;
        const int px = e - oc * 64;
        float s = bias[oc];
        #pragma unroll
        for (int w = 0; w < 4; ++w)
            s += red[(w * 64 + px) * OFFC + oc];
        offs[(size_t)b * OFFC * HW + (size_t)oc * HW + pix + px] = s;
    }
}

// ---------------------------------------------------------------------------
// Kernel 2: deformable grouped conv. One thread per (pixel, group):
// 9 taps x 8 input channels bilinear-sampled, accumulated into 8 outputs.
// g is wave-uniform (HW % 256 == 0) -> readfirstlane for scalar weight loads.
// ---------------------------------------------------------------------------
__global__ __launch_bounds__(256) void deform_conv(
    const float* __restrict__ x,      // (B, C, H, W) = input
    const float* __restrict__ offs,   // (B, 18, H, W)
    const float* __restrict__ w2t,    // [g][k][cg][og]
    float* __restrict__ out)          // (B, O, H, W)
{
    int idx = blockIdx.x * blockDim.x + threadIdx.x;
    int xw = idx % W;
    int yh = (idx / W) % H;
    int g = (idx / HW) % G;
    int b = idx / (HW * G);

    int gu = __builtin_amdgcn_readfirstlane(g);
    const float* wg = w2t + gu * (K * Cg * Og);
    const float* xg = x + ((size_t)b * C + gu * Cg) * HW;
    const float* offp = offs + (size_t)b * OFFC * HW + yh * W + xw;

    float acc[Og];
    #pragma unroll
    for (int og = 0; og < Og; ++og) acc[og] = 0.f;

    #pragma unroll
    for (int k = 0; k < K; ++k) {
        float dy = offp[(size_t)(2 * k) * HW];
        float dx = offp[(size_t)(2 * k + 1) * HW];
        float py = (float)(yh + k / 3 - 1) + dy;
        float px = (float)(xw + k % 3 - 1) + dx;
        float fy = floorf(py);
        float fx = floorf(px);
        int y0 = (int)fy, x0 = (int)fx;
        int y1 = y0 + 1, x1 = x0 + 1;
        float wy1 = py - fy, wx1 = px - fx;
        float wy0 = 1.f - wy1, wx0 = 1.f - wx1;
        bool vy0 = (y0 >= 0) & (y0 < H);
        bool vy1 = (y1 >= 0) & (y1 < H);
        bool vx0 = (x0 >= 0) & (x0 < W);
        bool vx1 = (x1 >= 0) & (x1 < W);
        float h00 = (vy0 & vx0) ? wy0 * wx0 : 0.f;
        float h01 = (vy0 & vx1) ? wy0 * wx1 : 0.f;
        float h10 = (vy1 & vx0) ? wy1 * wx0 : 0.f;
        float h11 = (vy1 & vx1) ? wy1 * wx1 : 0.f;
        int y0c = min(max(y0, 0), H - 1);
        int y1c = min(max(y1, 0), H - 1);
        int x0c = min(max(x0, 0), W - 1);
        int x1c = min(max(x1, 0), W - 1);
        int i00 = y0c * W + x0c;
        int i01 = y0c * W + x1c;
        int i10 = y1c * W + x0c;
        int i11 = y1c * W + x1c;
        const float* wk = wg + k * (Cg * Og);
        #pragma unroll
        for (int cg = 0; cg < Cg; ++cg) {
            const float* xc = xg + cg * HW;
            float v = h00 * xc[i00] + h01 * xc[i01]
                    + h10 * xc[i10] + h11 * xc[i11];
            #pragma unroll
            for (int og = 0; og < Og; ++og)
                acc[og] = fmaf(v, wk[cg * Og + og], acc[og]);
        }
    }
    float* op = out + ((size_t)b * O + gu * Og) * HW + yh * W + xw;
    #pragma unroll
    for (int og = 0; og < Og; ++og) op[(size_t)og * HW] = acc[og];
}

extern "C" void kernel_launch(void* const* d_in, const int* in_sizes, int n_in,
                              void* d_out, int out_size, void* d_ws, size_t ws_size,
                              hipStream_t stream) {
    const float* input       = (const float*)d_in[0];
    const float* offset_feat = (const float*)d_in[1];
    const float* weight      = (const float*)d_in[2];
    const float* off_w       = (const float*)d_in[3];
    const float* off_b       = (const float*)d_in[4];
    float* out = (float*)d_out;

    float* offs = (float*)d_ws;
    float* w1t = offs + OFF_ELEMS;
    float* w2t = w1t + W1_ELEMS;

    transpose_weights<<<(W1_ELEMS + 255) / 256, 256, 0, stream>>>(off_w, weight, w1t, w2t);
    offset_conv<<<(B * HW) / 64, 256, 0, stream>>>(offset_feat, w1t, off_b, offs);
    deform_conv<<<(B * G * HW) / 256, 256, 0, stream>>>(input, offs, w2t, out);
}

// Round 3
// 211.563 us; speedup vs baseline: 1.7609x; 1.7421x over previous
//
#include <hip/hip_runtime.h>

namespace {
constexpr int B = 2, C = 72, O = 72, H = 180, W = 320;
constexpr int K = 9, G = 9, Cg = 8, Og = 8;
constexpr int OFFC = 2 * K;           // 18 offset channels
constexpr int HW = H * W;             // 57600
constexpr size_t OFF_ELEMS = (size_t)B * OFFC * HW;   // 2,073,600 floats
constexpr int W1_ELEMS = OFFC * C * 9;                // 11664
constexpr int W2_ELEMS = O * Cg * 9;                  // 5184
constexpr int ICW = C / 4;            // 18 input channels per wave
}

// ---------------------------------------------------------------------------
// Setup: transpose weights for contiguous wave-uniform (scalar) access.
//   w1t[ic][tap][oc]   <- off_w[oc][ic][tap]      (18,72,3,3)
//   w2t[g][k][cg][og]  <- weight[g*8+og][cg][k]   (72,8,3,3)
// ---------------------------------------------------------------------------
__global__ __launch_bounds__(256) void transpose_weights(
    const float* __restrict__ off_w,
    const float* __restrict__ weight,
    float* __restrict__ w1t,
    float* __restrict__ w2t)
{
    int i = blockIdx.x * blockDim.x + threadIdx.x;
    if (i < W1_ELEMS) {
        int oc = i % OFFC;
        int tap = (i / OFFC) % 9;
        int ic = i / (OFFC * 9);
        w1t[i] = off_w[(oc * C + ic) * 9 + tap];
    }
    if (i < W2_ELEMS) {
        int og = i % Og;
        int cg = (i / Og) % Cg;
        int k = (i / (Og * Cg)) % K;
        int g = i / (Og * Cg * K);
        w2t[i] = weight[((g * Og + og) * Cg + cg) * 9 + k];
    }
}

// ---------------------------------------------------------------------------
// Kernel 1: 3x3 conv (C=72 -> 18) + bias.
// Block = 256 threads = 4 waves; block covers 64 consecutive pixels (one row
// segment, W % 64 == 0); wave w reduces input channels [18w, 18w+18).
// ic0 goes through readfirstlane so the compiler can PROVE wave-uniformity
// of the weight addresses -> s_load (SMEM) instead of per-lane VMEM loads.
// ---------------------------------------------------------------------------
__global__ __launch_bounds__(256, 8) void offset_conv(
    const float* __restrict__ x,      // (B, C, H, W) = offset_feat
    const float* __restrict__ w1t,    // [ic][tap][oc]
    const float* __restrict__ bias,   // (18,)
    float* __restrict__ offs)         // (B, 18, H, W)
{
    __shared__ float red[4 * 64 * OFFC];   // 18432 B
    const int lane = threadIdx.x & 63;
    const int wave = threadIdx.x >> 6;

    const int g0 = blockIdx.x * 64;        // pixel index over B*HW
    const int b = g0 / HW;
    const int pix = g0 - b * HW;           // multiple of 64; one row segment
    const int yh = pix / W;
    const int x0b = pix - yh * W;
    const int xw = x0b + lane;

    float acc[OFFC];
    #pragma unroll
    for (int oc = 0; oc < OFFC; ++oc) acc[oc] = 0.f;

    const float* xb = x + (size_t)b * C * HW;
    // readfirstlane: provably wave-uniform -> weight loads become scalar
    const int ic0 = __builtin_amdgcn_readfirstlane(wave * ICW);

    // row validity is wave-uniform (whole block is one image row)
    const bool rv0 = (yh - 1) >= 0;
    const bool rv2 = (yh + 1) < H;

    #pragma unroll 3
    for (int ici = 0; ici < ICW; ++ici) {
        const int ic = ic0 + ici;
        const float* xc = xb + ic * HW;
        #pragma unroll
        for (int ky = 0; ky < 3; ++ky) {
            const int yy = yh + ky - 1;
            const bool rowv = (ky == 0) ? rv0 : (ky == 2 ? rv2 : true);
            if (!rowv) continue;           // uniform branch
            const float* xr = xc + yy * W;
            #pragma unroll
            for (int kx = 0; kx < 3; ++kx) {
                const int xx = xw + kx - 1;
                const bool v = (xx >= 0) & (xx < W);
                const float val = v ? xr[xx] : 0.0f;
                const float* wp = w1t + (ic * 9 + ky * 3 + kx) * OFFC;
                #pragma unroll
                for (int oc = 0; oc < OFFC; ++oc)
                    acc[oc] = fmaf(val, wp[oc], acc[oc]);
            }
        }
    }

    #pragma unroll
    for (int oc = 0; oc < OFFC; ++oc)
        red[(wave * 64 + lane) * OFFC + oc] = acc[oc];
    __syncthreads();

    // 64*18 = 1152 outputs, 256 threads -> 4.5 elems each; px fast within oc
    for (int e = threadIdx.x; e < 64 * OFFC; e += 256) {
        const int oc = e / 64;
        const int px = e - oc * 64;
        float s = bias[oc];
        #pragma unroll
        for (int w = 0; w < 4; ++w)
            s += red[(w * 64 + px) * OFFC + oc];
        offs[(size_t)b * OFFC * HW + (size_t)oc * HW + pix + px] = s;
    }
}

// ---------------------------------------------------------------------------
// Kernel 2: deformable grouped conv. One thread per (pixel, group):
// 9 taps x 8 input channels bilinear-sampled, accumulated into 8 outputs.
// g is wave-uniform (HW % 256 == 0) -> readfirstlane for scalar weight loads.
// (unchanged this round: isolating the offset_conv change; counters next)
// ---------------------------------------------------------------------------
__global__ __launch_bounds__(256) void deform_conv(
    const float* __restrict__ x,      // (B, C, H, W) = input
    const float* __restrict__ offs,   // (B, 18, H, W)
    const float* __restrict__ w2t,    // [g][k][cg][og]
    float* __restrict__ out)          // (B, O, H, W)
{
    int idx = blockIdx.x * blockDim.x + threadIdx.x;
    int xw = idx % W;
    int yh = (idx / W) % H;
    int g = (idx / HW) % G;
    int b = idx / (HW * G);

    int gu = __builtin_amdgcn_readfirstlane(g);
    const float* wg = w2t + gu * (K * Cg * Og);
    const float* xg = x + ((size_t)b * C + gu * Cg) * HW;
    const float* offp = offs + (size_t)b * OFFC * HW + yh * W + xw;

    float acc[Og];
    #pragma unroll
    for (int og = 0; og < Og; ++og) acc[og] = 0.f;

    #pragma unroll
    for (int k = 0; k < K; ++k) {
        float dy = offp[(size_t)(2 * k) * HW];
        float dx = offp[(size_t)(2 * k + 1) * HW];
        float py = (float)(yh + k / 3 - 1) + dy;
        float px = (float)(xw + k % 3 - 1) + dx;
        float fy = floorf(py);
        float fx = floorf(px);
        int y0 = (int)fy, x0 = (int)fx;
        int y1 = y0 + 1, x1 = x0 + 1;
        float wy1 = py - fy, wx1 = px - fx;
        float wy0 = 1.f - wy1, wx0 = 1.f - wx1;
        bool vy0 = (y0 >= 0) & (y0 < H);
        bool vy1 = (y1 >= 0) & (y1 < H);
        bool vx0 = (x0 >= 0) & (x0 < W);
        bool vx1 = (x1 >= 0) & (x1 < W);
        float h00 = (vy0 & vx0) ? wy0 * wx0 : 0.f;
        float h01 = (vy0 & vx1) ? wy0 * wx1 : 0.f;
        float h10 = (vy1 & vx0) ? wy1 * wx0 : 0.f;
        float h11 = (vy1 & vx1) ? wy1 * wx1 : 0.f;
        int y0c = min(max(y0, 0), H - 1);
        int y1c = min(max(y1, 0), H - 1);
        int x0c = min(max(x0, 0), W - 1);
        int x1c = min(max(x1, 0), W - 1);
        int i00 = y0c * W + x0c;
        int i01 = y0c * W + x1c;
        int i10 = y1c * W + x0c;
        int i11 = y1c * W + x1c;
        const float* wk = wg + k * (Cg * Og);
        #pragma unroll
        for (int cg = 0; cg < Cg; ++cg) {
            const float* xc = xg + cg * HW;
            float v = h00 * xc[i00] + h01 * xc[i01]
                    + h10 * xc[i10] + h11 * xc[i11];
            #pragma unroll
            for (int og = 0; og < Og; ++og)
                acc[og] = fmaf(v, wk[cg * Og + og], acc[og]);
        }
    }
    float* op = out + ((size_t)b * O + gu * Og) * HW + yh * W + xw;
    #pragma unroll
    for (int og = 0; og < Og; ++og) op[(size_t)og * HW] = acc[og];
}

extern "C" void kernel_launch(void* const* d_in, const int* in_sizes, int n_in,
                              void* d_out, int out_size, void* d_ws, size_t ws_size,
                              hipStream_t stream) {
    const float* input       = (const float*)d_in[0];
    const float* offset_feat = (const float*)d_in[1];
    const float* weight      = (const float*)d_in[2];
    const float* off_w       = (const float*)d_in[3];
    const float* off_b       = (const float*)d_in[4];
    float* out = (float*)d_out;

    float* offs = (float*)d_ws;
    float* w1t = offs + OFF_ELEMS;
    float* w2t = w1t + W1_ELEMS;

    transpose_weights<<<(W1_ELEMS + 255) / 256, 256, 0, stream>>>(off_w, weight, w1t, w2t);
    offset_conv<<<(B * HW) / 64, 256, 0, stream>>>(offset_feat, w1t, off_b, offs);
    deform_conv<<<(B * G * HW) / 256, 256, 0, stream>>>(input, offs, w2t, out);
}

// Round 4
// 173.106 us; speedup vs baseline: 2.1520x; 1.2222x over previous
//
#include <hip/hip_runtime.h>

namespace {
constexpr int B = 2, C = 72, O = 72, H = 180, W = 320;
constexpr int K = 9, G = 9, Cg = 8, Og = 8;
constexpr int OFFC = 2 * K;           // 18 offset channels
constexpr int HW = H * W;             // 57600
constexpr size_t OFF_ELEMS = (size_t)B * OFFC * HW;   // 2,073,600 floats
constexpr int W1_ELEMS = OFFC * C * 9;                // 11664
constexpr int W2_ELEMS = O * Cg * 9;                  // 5184
constexpr int ICW = C / 4;            // 18 input channels per wave

// 8-byte vector load with only 4-byte alignment guarantee (gfx9+ supports
// misaligned global dwordx2; LLVM splits it if not).
typedef float f2u __attribute__((ext_vector_type(2), aligned(4)));
}

// ---------------------------------------------------------------------------
// Setup: transpose weights for contiguous wave-uniform (scalar) access.
//   w1t[ic][tap][oc]   <- off_w[oc][ic][tap]      (18,72,3,3)
//   w2t[g][k][cg][og]  <- weight[g*8+og][cg][k]   (72,8,3,3)
// ---------------------------------------------------------------------------
__global__ __launch_bounds__(256) void transpose_weights(
    const float* __restrict__ off_w,
    const float* __restrict__ weight,
    float* __restrict__ w1t,
    float* __restrict__ w2t)
{
    int i = blockIdx.x * blockDim.x + threadIdx.x;
    if (i < W1_ELEMS) {
        int oc = i % OFFC;
        int tap = (i / OFFC) % 9;
        int ic = i / (OFFC * 9);
        w1t[i] = off_w[(oc * C + ic) * 9 + tap];
    }
    if (i < W2_ELEMS) {
        int og = i % Og;
        int cg = (i / Og) % Cg;
        int k = (i / (Og * Cg)) % K;
        int g = i / (Og * Cg * K);
        w2t[i] = weight[((g * Og + og) * Cg + cg) * 9 + k];
    }
}

// ---------------------------------------------------------------------------
// Kernel 1: 3x3 conv (C=72 -> 18) + bias. 4 waves split C; LDS reduce.
// ic0 via readfirstlane -> provably wave-uniform weight addrs -> s_load.
// ---------------------------------------------------------------------------
__global__ __launch_bounds__(256, 8) void offset_conv(
    const float* __restrict__ x,      // (B, C, H, W) = offset_feat
    const float* __restrict__ w1t,    // [ic][tap][oc]
    const float* __restrict__ bias,   // (18,)
    float* __restrict__ offs)         // (B, 18, H, W)
{
    __shared__ float red[4 * 64 * OFFC];   // 18432 B
    const int lane = threadIdx.x & 63;
    const int wave = threadIdx.x >> 6;

    const int g0 = blockIdx.x * 64;        // pixel index over B*HW
    const int b = g0 / HW;
    const int pix = g0 - b * HW;           // multiple of 64; one row segment
    const int yh = pix / W;
    const int x0b = pix - yh * W;
    const int xw = x0b + lane;

    float acc[OFFC];
    #pragma unroll
    for (int oc = 0; oc < OFFC; ++oc) acc[oc] = 0.f;

    const float* xb = x + (size_t)b * C * HW;
    const int ic0 = __builtin_amdgcn_readfirstlane(wave * ICW);

    const bool rv0 = (yh - 1) >= 0;
    const bool rv2 = (yh + 1) < H;

    #pragma unroll 3
    for (int ici = 0; ici < ICW; ++ici) {
        const int ic = ic0 + ici;
        const float* xc = xb + ic * HW;
        #pragma unroll
        for (int ky = 0; ky < 3; ++ky) {
            const int yy = yh + ky - 1;
            const bool rowv = (ky == 0) ? rv0 : (ky == 2 ? rv2 : true);
            if (!rowv) continue;           // uniform branch
            const float* xr = xc + yy * W;
            #pragma unroll
            for (int kx = 0; kx < 3; ++kx) {
                const int xx = xw + kx - 1;
                const bool v = (xx >= 0) & (xx < W);
                const float val = v ? xr[xx] : 0.0f;
                const float* wp = w1t + (ic * 9 + ky * 3 + kx) * OFFC;
                #pragma unroll
                for (int oc = 0; oc < OFFC; ++oc)
                    acc[oc] = fmaf(val, wp[oc], acc[oc]);
            }
        }
    }

    #pragma unroll
    for (int oc = 0; oc < OFFC; ++oc)
        red[(wave * 64 + lane) * OFFC + oc] = acc[oc];
    __syncthreads();

    for (int e = threadIdx.x; e < 64 * OFFC; e += 256) {
        const int oc = e / 64;
        const int px = e - oc * 64;
        float s = bias[oc];
        #pragma unroll
        for (int w = 0; w < 4; ++w)
            s += red[(w * 64 + px) * OFFC + oc];
        offs[(size_t)b * OFFC * HW + (size_t)oc * HW + pix + px] = s;
    }
}

// ---------------------------------------------------------------------------
// Kernel 2: deformable grouped conv. One thread per (pixel, group).
// This round: (a) all 18 offset loads hoisted (MLP), (b) the 2x2 bilinear
// neighborhood loaded as TWO paired-column dwordx2 per channel instead of
// four scalar gathers; clamp/validity folded into component selects and
// zeroed weights. 306 -> 162 VMEM loads per thread.
// ---------------------------------------------------------------------------
__global__ __launch_bounds__(256) void deform_conv(
    const float* __restrict__ x,      // (B, C, H, W) = input
    const float* __restrict__ offs,   // (B, 18, H, W)
    const float* __restrict__ w2t,    // [g][k][cg][og]
    float* __restrict__ out)          // (B, O, H, W)
{
    int idx = blockIdx.x * blockDim.x + threadIdx.x;
    int xw = idx % W;
    int yh = (idx / W) % H;
    int g = (idx / HW) % G;
    int b = idx / (HW * G);

    int gu = __builtin_amdgcn_readfirstlane(g);
    const float* wg = w2t + gu * (K * Cg * Og);
    const float* xg = x + ((size_t)b * C + gu * Cg) * HW;
    const float* offp = offs + (size_t)b * OFFC * HW + yh * W + xw;

    // Hoist all offset loads: 18 coalesced loads in flight at once.
    float dy[K], dx[K];
    #pragma unroll
    for (int k = 0; k < K; ++k) {
        dy[k] = offp[(size_t)(2 * k) * HW];
        dx[k] = offp[(size_t)(2 * k + 1) * HW];
    }

    float acc[Og];
    #pragma unroll
    for (int og = 0; og < Og; ++og) acc[og] = 0.f;

    #pragma unroll
    for (int k = 0; k < K; ++k) {
        float py = (float)(yh + k / 3 - 1) + dy[k];
        float px = (float)(xw + k % 3 - 1) + dx[k];
        float fy = floorf(py);
        float fx = floorf(px);
        int y0 = (int)fy, x0 = (int)fx;
        float wy1 = py - fy, wx1 = px - fx;
        float wy0 = 1.f - wy1, wx0 = 1.f - wx1;
        // validity -> folded into weights (invalid taps contribute 0)
        float hy0 = ((y0 >= 0) & (y0 < H)) ? wy0 : 0.f;
        float hy1 = ((y0 + 1 >= 0) & (y0 + 1 < H)) ? wy1 : 0.f;
        float gx0 = ((x0 >= 0) & (x0 < W)) ? wx0 : 0.f;
        float gx1 = ((x0 + 1 >= 0) & (x0 + 1 < W)) ? wx1 : 0.f;
        int y0c = min(max(y0, 0), H - 1);
        int y1c = min(max(y0 + 1, 0), H - 1);
        int x0c = min(max(x0, 0), W - 1);
        int x1c = min(max(x0 + 1, 0), W - 1);
        int xbase = min(max(x0, 0), W - 2);     // pair {xbase, xbase+1}
        bool selA = (x0c == xbase);             // v00 from .x else .y
        bool selB = (x1c == xbase + 1);         // v01 from .y else .x
        int r0 = y0c * W + xbase;
        int r1 = y1c * W + xbase;
        const float* wk = wg + k * (Cg * Og);
        #pragma unroll
        for (int cg = 0; cg < Cg; ++cg) {
            const float* xc = xg + cg * HW;
            f2u a0 = *(const f2u*)(xc + r0);
            f2u a1 = *(const f2u*)(xc + r1);
            float v00 = selA ? a0.x : a0.y;
            float v01 = selB ? a0.y : a0.x;
            float v10 = selA ? a1.x : a1.y;
            float v11 = selB ? a1.y : a1.x;
            float row0 = fmaf(gx1, v01, gx0 * v00);
            float row1 = fmaf(gx1, v11, gx0 * v10);
            float v = fmaf(hy1, row1, hy0 * row0);
            #pragma unroll
            for (int og = 0; og < Og; ++og)
                acc[og] = fmaf(v, wk[cg * Og + og], acc[og]);
        }
    }
    float* op = out + ((size_t)b * O + gu * Og) * HW + yh * W + xw;
    #pragma unroll
    for (int og = 0; og < Og; ++og) op[(size_t)og * HW] = acc[og];
}

extern "C" void kernel_launch(void* const* d_in, const int* in_sizes, int n_in,
                              void* d_out, int out_size, void* d_ws, size_t ws_size,
                              hipStream_t stream) {
    const float* input       = (const float*)d_in[0];
    const float* offset_feat = (const float*)d_in[1];
    const float* weight      = (const float*)d_in[2];
    const float* off_w       = (const float*)d_in[3];
    const float* off_b       = (const float*)d_in[4];
    float* out = (float*)d_out;

    float* offs = (float*)d_ws;
    float* w1t = offs + OFF_ELEMS;
    float* w2t = w1t + W1_ELEMS;

    transpose_weights<<<(W1_ELEMS + 255) / 256, 256, 0, stream>>>(off_w, weight, w1t, w2t);
    offset_conv<<<(B * HW) / 64, 256, 0, stream>>>(offset_feat, w1t, off_b, offs);
    deform_conv<<<(B * G * HW) / 256, 256, 0, stream>>>(input, offs, w2t, out);
}